// Round 8
// baseline (111.974 us; speedup 1.0000x reference)
//
#include <hip/hip_runtime.h>
#include <hip/hip_cooperative_groups.h>

namespace cg = cooperative_groups;

#define BB 32
#define TT 2048
#define HH 1024
#define KK 11
#define PD 5

// ---------------- Single cooperative kernel -------------------------------------
// grid (NC, B), all blocks co-resident (host verifies via occupancy query).
// Phase 1: block (c,b) streams its TC=T/NC rows of eh once; wave-owns-row dot +
//   6-shfl butterfly; per-wave online softmax; scores kept in LDS (no stash).
// grid.sync()
// Phase 2: each block folds the per-chunk (m,Z) table, writes ax_new for its own
//   chunk from LDS scores, and one H-slice of sx (NC-way parallel combine).
__global__ __launch_bounds__(256) void fused_coop_kernel(
    const float* __restrict__ eh, const float* __restrict__ dhx,
    const float* __restrict__ ax, const float* __restrict__ conv_w,
    const float* __restrict__ conv_b,
    float* __restrict__ mArr, float* __restrict__ ZArr,
    float* __restrict__ part,
    float* __restrict__ sx, float* __restrict__ ax_new) {
    const int NC = gridDim.x;
    const int TC = TT / NC;
    const int ROWS = TC / 4;  // rows per wave
    const int c = blockIdx.x, b = blockIdx.y;
    const int t0 = c * TC;
    const int tid = threadIdx.x;
    const int wave = tid >> 6, lane = tid & 63;

    extern __shared__ float sm[];
    float* wsh   = sm;          // 16: conv weights
    float* mz    = sm + 16;     // 8: per-wave m, Z
    float* mS    = sm + 24;     // 64: per-chunk m (phase 2)
    float* zS    = sm + 88;     // 64: per-chunk Z -> weights (phase 2)
    float* sS    = sm + 152;    // TC: conv loc, then raw scores
    float* P_lds = sm + 152 + TC;  // 4*HH: wave partials (phase1) / red (phase2)

    // ---- conv location scores into sS ----
    if (tid < KK) wsh[tid] = conv_w[tid];
    __syncthreads();
    const float cbv = conv_b[0];
    for (int i = tid; i < TC; i += 256) {
        float acc = cbv;
#pragma unroll
        for (int k = 0; k < KK; ++k) {
            int t = t0 + i - PD + k;
            float a = (t >= 0 && t < TT) ? ax[(size_t)b * TT + t] : 0.f;
            acc += a * wsh[k];
        }
        sS[i] = acc;
    }
    __syncthreads();

    const float4* dh4 = reinterpret_cast<const float4*>(dhx) + b * (HH / 4);
    float4 dh[4];
#pragma unroll
    for (int j = 0; j < 4; ++j) dh[j] = dh4[j * 64 + lane];

    const float4* e4 =
        reinterpret_cast<const float4*>(eh) + ((size_t)b * TT + t0) * (HH / 4);

    float m = -INFINITY, Z = 0.f;
    float4 P[4];
#pragma unroll
    for (int j = 0; j < 4; ++j) P[j] = make_float4(0.f, 0.f, 0.f, 0.f);

    float4 cur[4];
    {
        const float4* rp = e4 + (size_t)wave * (HH / 4);
#pragma unroll
        for (int j = 0; j < 4; ++j) cur[j] = rp[j * 64 + lane];
    }

    for (int i = 0; i < ROWS; ++i) {
        float4 nxt[4];
        if (i + 1 < ROWS) {  // uniform branch
            const float4* rq = e4 + (size_t)((i + 1) * 4 + wave) * (HH / 4);
#pragma unroll
            for (int j = 0; j < 4; ++j) nxt[j] = rq[j * 64 + lane];
        }

        float s = 0.f;
#pragma unroll
        for (int j = 0; j < 4; ++j)
            s += cur[j].x * dh[j].x + cur[j].y * dh[j].y + cur[j].z * dh[j].z +
                 cur[j].w * dh[j].w;
#pragma unroll
        for (int off = 1; off < 64; off <<= 1) s += __shfl_xor(s, off, 64);
        s += sS[i * 4 + wave];                       // add loc (LDS read)
        if (lane == 0) sS[i * 4 + wave] = s;         // keep raw score in LDS

        if (s > m) {  // wave-uniform
            float sc = __expf(m - s);
            Z *= sc;
#pragma unroll
            for (int j = 0; j < 4; ++j) {
                P[j].x *= sc; P[j].y *= sc; P[j].z *= sc; P[j].w *= sc;
            }
            m = s;
        }
        float p = __expf(s - m);
        Z += p;
#pragma unroll
        for (int j = 0; j < 4; ++j) {
            P[j].x += p * cur[j].x; P[j].y += p * cur[j].y;
            P[j].z += p * cur[j].z; P[j].w += p * cur[j].w;
        }

        if (i + 1 < ROWS) {
#pragma unroll
            for (int j = 0; j < 4; ++j) cur[j] = nxt[j];
        }
    }

    // ---- combine 4 waves ----
    if (lane == 0) { mz[wave] = m; mz[4 + wave] = Z; }
    __syncthreads();
    const float mb = fmaxf(fmaxf(mz[0], mz[1]), fmaxf(mz[2], mz[3]));
    const float sc = __expf(m - mb);  // wave-uniform
    float4* Pl4 = reinterpret_cast<float4*>(P_lds);
#pragma unroll
    for (int j = 0; j < 4; ++j) {
        float4 q = P[j];
        q.x *= sc; q.y *= sc; q.z *= sc; q.w *= sc;
        Pl4[wave * 256 + j * 64 + lane] = q;
    }
    __syncthreads();
    float4 a0 = Pl4[tid], a1 = Pl4[256 + tid], a2 = Pl4[512 + tid],
           a3 = Pl4[768 + tid];
    float4 acc4;
    acc4.x = a0.x + a1.x + a2.x + a3.x;
    acc4.y = a0.y + a1.y + a2.y + a3.y;
    acc4.z = a0.z + a1.z + a2.z + a3.z;
    acc4.w = a0.w + a1.w + a2.w + a3.w;
    reinterpret_cast<float4*>(part)[((size_t)b * NC + c) * 256 + tid] = acc4;

    if (tid == 0) {
        float Zb = 0.f;
#pragma unroll
        for (int w = 0; w < 4; ++w) Zb += __expf(mz[w] - mb) * mz[4 + w];
        mArr[b * NC + c] = mb;
        ZArr[b * NC + c] = Zb;
    }

    // ================= grid-wide sync =================
    cg::this_grid().sync();

    // ---- phase 2: fold (m,Z) table for batch b ----
    if (tid < NC) { mS[tid] = mArr[b * NC + tid]; zS[tid] = ZArr[b * NC + tid]; }
    __syncthreads();
    float mg = -INFINITY;
    for (int cc = 0; cc < NC; ++cc) mg = fmaxf(mg, mS[cc]);
    float Zg = 0.f;
    for (int cc = 0; cc < NC; ++cc) Zg += __expf(mS[cc] - mg) * zS[cc];
    const float invZ = 1.f / Zg;
    __syncthreads();
    if (tid < NC) zS[tid] = __expf(mS[tid] - mg) * invZ;  // per-chunk weight
    __syncthreads();

    // ax_new for own chunk, straight from LDS scores
    if (tid < TC)
        ax_new[(size_t)b * TT + t0 + tid] = __expf(sS[tid] - mg) * invZ;

    // sx: this block owns h-slice [c*HS, (c+1)*HS)
    const int HS = HH / NC;        // 16 (NC=64) or 32 (NC=32)
    const int G = 256 / HS;        // groups
    const int hl = tid & (HS - 1);
    const int g = tid / HS;
    float acc = 0.f;
    for (int cc = g; cc < NC; cc += G)
        acc += zS[cc] * part[((size_t)b * NC + cc) * HH + c * HS + hl];
    P_lds[g * HS + hl] = acc;
    __syncthreads();
    if (tid < HS) {
        float a = 0.f;
        for (int gg = 0; gg < G; ++gg) a += P_lds[gg * HS + tid];
        sx[(size_t)b * HH + c * HS + tid] = a;
    }
}

extern "C" void kernel_launch(void* const* d_in, const int* in_sizes, int n_in,
                              void* d_out, int out_size, void* d_ws, size_t ws_size,
                              hipStream_t stream) {
    const float* eh  = (const float*)d_in[0];
    const float* dhx = (const float*)d_in[1];
    const float* ax  = (const float*)d_in[2];
    const float* cw  = (const float*)d_in[3];
    const float* cb  = (const float*)d_in[4];

    float* out    = (float*)d_out;
    float* sx     = out;            // (B,1,H)
    float* ax_new = out + BB * HH;  // (B,T)

    // pick NC so the whole cooperative grid is co-resident (and ws fits)
    int nc = 64;
    for (;;) {
        const int TC = TT / nc;
        const size_t lds = (152 + TC + 4 * HH) * sizeof(float);
        int mbk = 0;
        hipOccupancyMaxActiveBlocksPerMultiprocessor(&mbk, fused_coop_kernel, 256,
                                                     lds);
        const bool resident = (size_t)mbk * 256 >= (size_t)nc * BB;  // 256 CUs
        const bool fits =
            (2ull * BB * nc + 4096 + (size_t)BB * nc * HH) * 4 <= ws_size;
        if ((resident && fits) || nc <= 8) break;
        nc >>= 1;
    }

    float* mArr = (float*)d_ws;              // B*nc
    float* ZArr = mArr + (size_t)BB * nc;    // B*nc
    float* part = (float*)d_ws + 4096;       // B*nc*H, 16 KB offset (aligned)

    const int TC = TT / nc;
    const size_t lds_bytes = (152 + TC + 4 * HH) * sizeof(float);

    dim3 grid(nc, BB), block(256, 1, 1);
    void* args[] = {(void*)&eh, (void*)&dhx, (void*)&ax,   (void*)&cw,
                    (void*)&cb, (void*)&mArr, (void*)&ZArr, (void*)&part,
                    (void*)&sx, (void*)&ax_new};
    hipLaunchCooperativeKernel((const void*)fused_coop_kernel, grid, block, args,
                               (unsigned int)lds_bytes, stream);
}

// Round 9
// 56.012 us; speedup vs baseline: 1.9991x; 1.9991x over previous
//
#include <hip/hip_runtime.h>

#define BB 32
#define TT 2048
#define HH 1024
#define KK 11
#define PD 5

// ---------------- Fused main kernel (R7, proven 57.3us) --------------------------
// grid (NC, B): block owns chunk c (TC = T/NC rows) of batch b.
// Each WAVE owns every 4th row (64 lanes x 4 float4 = full H row). Row dot =
// 16 lane FMAs + 6-shfl butterfly; no barriers/LDS in the main loop; per-wave
// online softmax; one LDS combine at end.
// NOTE: no min-waves clause — __launch_bounds__(256,8) caps VGPR at 32 and
// spills (R6: FETCH +124MB, 1.9 TB/s). VGPR=56 keeps 8 waves/SIMD naturally.
__global__ __launch_bounds__(256) void fused_main_kernel(
    const float* __restrict__ eh, const float* __restrict__ dhx,
    const float* __restrict__ ax, const float* __restrict__ conv_w,
    const float* __restrict__ conv_b,
    float* __restrict__ stash, float* __restrict__ mArr,
    float* __restrict__ ZArr, float* __restrict__ part) {
    const int NC = gridDim.x;
    const int TC = TT / NC;
    const int ROWS = TC / 4;  // rows per wave
    const int c = blockIdx.x, b = blockIdx.y;
    const int t0 = c * TC;
    const int tid = threadIdx.x;
    const int wave = tid >> 6, lane = tid & 63;

    extern __shared__ float sm[];
    float* wsh    = sm;            // 16: conv weights
    float* mz     = sm + 16;       // 8: per-wave m, Z
    float* loc_sh = sm + 24;       // TC: conv output
    float* P_lds  = sm + 24 + TC;  // 4*HH: per-wave scaled partials

    if (tid < KK) wsh[tid] = conv_w[tid];
    __syncthreads();
    const float cb = conv_b[0];
    for (int i = tid; i < TC; i += 256) {
        float acc = cb;
#pragma unroll
        for (int k = 0; k < KK; ++k) {
            int t = t0 + i - PD + k;
            float a = (t >= 0 && t < TT) ? ax[(size_t)b * TT + t] : 0.f;
            acc += a * wsh[k];
        }
        loc_sh[i] = acc;
    }
    __syncthreads();

    const float4* dh4 = reinterpret_cast<const float4*>(dhx) + b * (HH / 4);
    float4 dh[4];
#pragma unroll
    for (int j = 0; j < 4; ++j) dh[j] = dh4[j * 64 + lane];

    const float4* e4 =
        reinterpret_cast<const float4*>(eh) + ((size_t)b * TT + t0) * (HH / 4);

    float m = -INFINITY, Z = 0.f;
    float4 P[4];
#pragma unroll
    for (int j = 0; j < 4; ++j) P[j] = make_float4(0.f, 0.f, 0.f, 0.f);

    float4 cur[4];
    {
        const float4* rp = e4 + (size_t)wave * (HH / 4);
#pragma unroll
        for (int j = 0; j < 4; ++j) cur[j] = rp[j * 64 + lane];
    }

    for (int i = 0; i < ROWS; ++i) {
        float4 nxt[4];
        if (i + 1 < ROWS) {  // uniform branch
            const float4* rq = e4 + (size_t)((i + 1) * 4 + wave) * (HH / 4);
#pragma unroll
            for (int j = 0; j < 4; ++j) nxt[j] = rq[j * 64 + lane];
        }

        float s = 0.f;
#pragma unroll
        for (int j = 0; j < 4; ++j)
            s += cur[j].x * dh[j].x + cur[j].y * dh[j].y + cur[j].z * dh[j].z +
                 cur[j].w * dh[j].w;
#pragma unroll
        for (int off = 1; off < 64; off <<= 1) s += __shfl_xor(s, off, 64);
        s += loc_sh[i * 4 + wave];

        if (lane == 0) stash[(size_t)b * TT + t0 + i * 4 + wave] = s;

        if (s > m) {  // wave-uniform
            float sc = __expf(m - s);
            Z *= sc;
#pragma unroll
            for (int j = 0; j < 4; ++j) {
                P[j].x *= sc; P[j].y *= sc; P[j].z *= sc; P[j].w *= sc;
            }
            m = s;
        }
        float p = __expf(s - m);
        Z += p;
#pragma unroll
        for (int j = 0; j < 4; ++j) {
            P[j].x += p * cur[j].x; P[j].y += p * cur[j].y;
            P[j].z += p * cur[j].z; P[j].w += p * cur[j].w;
        }

        if (i + 1 < ROWS) {
#pragma unroll
            for (int j = 0; j < 4; ++j) cur[j] = nxt[j];
        }
    }

    // ---- combine 4 waves (2 barriers) ----
    if (lane == 0) { mz[wave] = m; mz[4 + wave] = Z; }
    __syncthreads();
    const float mb = fmaxf(fmaxf(mz[0], mz[1]), fmaxf(mz[2], mz[3]));
    const float sc = __expf(m - mb);  // wave-uniform
    float4* Pl4 = reinterpret_cast<float4*>(P_lds);
#pragma unroll
    for (int j = 0; j < 4; ++j) {
        float4 q = P[j];
        q.x *= sc; q.y *= sc; q.z *= sc; q.w *= sc;
        Pl4[wave * 256 + j * 64 + lane] = q;
    }
    __syncthreads();
    float4 a0 = Pl4[tid], a1 = Pl4[256 + tid], a2 = Pl4[512 + tid],
           a3 = Pl4[768 + tid];
    float4 acc;
    acc.x = a0.x + a1.x + a2.x + a3.x;
    acc.y = a0.y + a1.y + a2.y + a3.y;
    acc.z = a0.z + a1.z + a2.z + a3.z;
    acc.w = a0.w + a1.w + a2.w + a3.w;
    reinterpret_cast<float4*>(part)[((size_t)b * NC + c) * 256 + tid] = acc;

    if (tid == 0) {
        float Zb = 0.f;
#pragma unroll
        for (int w = 0; w < 4; ++w) Zb += __expf(mz[w] - mb) * mz[4 + w];
        mArr[b * NC + c] = mb;
        ZArr[b * NC + c] = Zb;
    }
}

// ---------------- Tail: sx combine (4-way parallel) + ax_new --------------------
// grid (5, B): blockIdx.x<4 -> sx h-slice [x*256,(x+1)*256); ==4 -> ax_new.
// Each sx block reads only NC x 256 floats (64 KB), scalar-coalesced (1KB per
// cc per load round), unrolled x8 so loads pipeline.
__global__ __launch_bounds__(256) void tail_kernel(
    const float* __restrict__ mArr, const float* __restrict__ ZArr,
    const float* __restrict__ part, const float* __restrict__ stash,
    float* __restrict__ sx, float* __restrict__ ax_new, int NC) {
    const int b = blockIdx.y;
    const int tid = threadIdx.x;
    __shared__ float mS[64], wS[64];

    if (tid < NC) { mS[tid] = mArr[b * NC + tid]; wS[tid] = ZArr[b * NC + tid]; }
    __syncthreads();
    float mg = -INFINITY;
    for (int cc = 0; cc < NC; ++cc) mg = fmaxf(mg, mS[cc]);
    float Zg = 0.f;
    for (int cc = 0; cc < NC; ++cc) Zg += __expf(mS[cc] - mg) * wS[cc];
    const float invZ = 1.f / Zg;
    __syncthreads();
    if (tid < NC) wS[tid] = __expf(mS[tid] - mg) * invZ;  // per-chunk weight
    __syncthreads();

    if (blockIdx.x < 4) {
        const int h = blockIdx.x * 256 + tid;
        const float* pb = part + (size_t)b * NC * HH + h;
        float acc = 0.f;
        for (int cc = 0; cc < NC; cc += 8) {
#pragma unroll
            for (int u = 0; u < 8; ++u)
                acc += wS[cc + u] * pb[(size_t)(cc + u) * HH];
        }
        sx[(size_t)b * HH + h] = acc;
    } else {
        float v[8];
#pragma unroll
        for (int j = 0; j < 8; ++j) v[j] = stash[(size_t)b * TT + j * 256 + tid];
#pragma unroll
        for (int j = 0; j < 8; ++j)
            ax_new[(size_t)b * TT + j * 256 + tid] = __expf(v[j] - mg) * invZ;
    }
}

extern "C" void kernel_launch(void* const* d_in, const int* in_sizes, int n_in,
                              void* d_out, int out_size, void* d_ws, size_t ws_size,
                              hipStream_t stream) {
    const float* eh  = (const float*)d_in[0];
    const float* dhx = (const float*)d_in[1];
    const float* ax  = (const float*)d_in[2];
    const float* cw  = (const float*)d_in[3];
    const float* cb  = (const float*)d_in[4];

    float* out    = (float*)d_out;
    float* sx     = out;            // (B,1,H)
    float* ax_new = out + BB * HH;  // (B,T)

    int nc = 64;  // 2048 blocks = 8 blocks/CU on 256 CUs (32 waves/CU)
    while (nc > 8 &&
           ((size_t)BB * TT + 2ull * BB * nc + (size_t)BB * nc * HH + 64) * 4 > ws_size)
        nc >>= 1;

    float* stash = (float*)d_ws;             // B*T
    float* mArr  = stash + (size_t)BB * TT;  // B*nc
    float* ZArr  = mArr + (size_t)BB * nc;   // B*nc
    float* part  = ZArr + (size_t)BB * nc;   // B*nc*H (16B-aligned)

    const int TC = TT / nc;
    const size_t lds_bytes = (24 + TC + 4 * HH) * sizeof(float);

    dim3 gmain(nc, BB);
    fused_main_kernel<<<gmain, 256, lds_bytes, stream>>>(eh, dhx, ax, cw, cb,
                                                         stash, mArr, ZArr, part);
    dim3 gtail(5, BB);
    tail_kernel<<<gtail, 256, 0, stream>>>(mArr, ZArr, part, stash, sx, ax_new, nc);
}